// Round 1
// baseline (832.057 us; speedup 1.0000x reference)
//
#include <hip/hip_runtime.h>

typedef __attribute__((ext_vector_type(8))) short short8;
typedef __attribute__((ext_vector_type(4))) float f32x4;
typedef __attribute__((ext_vector_type(4))) unsigned short u16x4;

__device__ __forceinline__ unsigned short f2bf(float f){
  unsigned int u = __builtin_bit_cast(unsigned int, f);
  u = (u + 0x7FFFu + ((u >> 16) & 1u)) >> 16;
  return (unsigned short)u;
}
__device__ __forceinline__ float bf2f(unsigned short h){
  unsigned int u = ((unsigned int)h) << 16;
  return __builtin_bit_cast(float, u);
}
__device__ __forceinline__ f32x4 mfma16(short8 a, short8 b, f32x4 c){
  return __builtin_amdgcn_mfma_f32_16x16x32_bf16(a, b, c, 0, 0, 0);
}

// ---------------- f32 -> bf16 weight conversion (exactly 512*512 elems) ----
__global__ __launch_bounds__(256) void cvt_f32_bf16(const float* __restrict__ src,
                                                    unsigned short* __restrict__ dst){
  int i = (blockIdx.x * 256 + threadIdx.x) * 4;
  float4 v = *(const float4*)(src + i);
  u16x4 o = { f2bf(v.x), f2bf(v.y), f2bf(v.z), f2bf(v.w) };
  *(u16x4*)(dst + i) = o;
}

// ---------------- LayerNorm over D=512, one wave per row, bf16 out --------
__global__ __launch_bounds__(256) void ln_rows(const float* __restrict__ x,
                                               const float* __restrict__ g,
                                               const float* __restrict__ b,
                                               unsigned short* __restrict__ y,
                                               int nrows){
  const int wid = threadIdx.x >> 6, lane = threadIdx.x & 63;
  const int row = blockIdx.x * 4 + wid;
  if (row >= nrows) return;
  const float* xr = x + (long)row * 512;
  float4 v0 = *(const float4*)(xr + lane * 4);
  float4 v1 = *(const float4*)(xr + 256 + lane * 4);
  float s  = v0.x + v0.y + v0.z + v0.w + v1.x + v1.y + v1.z + v1.w;
  float s2 = v0.x*v0.x + v0.y*v0.y + v0.z*v0.z + v0.w*v0.w
           + v1.x*v1.x + v1.y*v1.y + v1.z*v1.z + v1.w*v1.w;
  #pragma unroll
  for (int m = 1; m < 64; m <<= 1){ s += __shfl_xor(s, m); s2 += __shfl_xor(s2, m); }
  const float mu = s * (1.f/512.f);
  const float rstd = rsqrtf(s2 * (1.f/512.f) - mu*mu + 1e-5f);
  float4 g0 = *(const float4*)(g + lane*4), g1 = *(const float4*)(g + 256 + lane*4);
  float4 b0 = *(const float4*)(b + lane*4), b1 = *(const float4*)(b + 256 + lane*4);
  u16x4 o0 = { f2bf((v0.x-mu)*rstd*g0.x + b0.x), f2bf((v0.y-mu)*rstd*g0.y + b0.y),
               f2bf((v0.z-mu)*rstd*g0.z + b0.z), f2bf((v0.w-mu)*rstd*g0.w + b0.w) };
  u16x4 o1 = { f2bf((v1.x-mu)*rstd*g1.x + b1.x), f2bf((v1.y-mu)*rstd*g1.y + b1.y),
               f2bf((v1.z-mu)*rstd*g1.z + b1.z), f2bf((v1.w-mu)*rstd*g1.w + b1.w) };
  *(u16x4*)(y + (long)row * 512 + lane * 4) = o0;
  *(u16x4*)(y + (long)row * 512 + 256 + lane * 4) = o1;
}

// ---------------- C = A(rows x 512) * B(512 x 512)^T + bias,  bf16 --------
// transposed==1: writes vT layout out[(m*512 + col)*128 + s], m=row>>7, s=row&127
__global__ __launch_bounds__(256) void gemm_bt(const unsigned short* __restrict__ A,
                                               const unsigned short* __restrict__ B,
                                               const float* __restrict__ bias,
                                               unsigned short* __restrict__ out,
                                               int transposed){
  __shared__ unsigned short At[128][40];
  __shared__ unsigned short Bt[128][40];
  const int t = threadIdx.x, lane = t & 63, wid = t >> 6;
  const int l15 = lane & 15, l4 = lane >> 4;
  const int wr = wid >> 1, wc = wid & 1;
  const int rowBase = blockIdx.y * 128;
  const int colBase = blockIdx.x * 128;
  f32x4 zero = {0.f, 0.f, 0.f, 0.f};
  f32x4 acc[4][4];
  #pragma unroll
  for (int i = 0; i < 4; ++i)
    #pragma unroll
    for (int j = 0; j < 4; ++j) acc[i][j] = zero;
  const int sr = t >> 1, sh = (t & 1) * 16;
  for (int ks = 0; ks < 16; ++ks){
    const int k0 = ks * 32;
    const unsigned short* sa = A + (long)(rowBase + sr) * 512 + k0 + sh;
    *(short8*)&At[sr][sh]     = *(const short8*)sa;
    *(short8*)&At[sr][sh + 8] = *(const short8*)(sa + 8);
    const unsigned short* sb = B + (long)(colBase + sr) * 512 + k0 + sh;
    *(short8*)&Bt[sr][sh]     = *(const short8*)sb;
    *(short8*)&Bt[sr][sh + 8] = *(const short8*)(sb + 8);
    __syncthreads();
    short8 af[4], bfv[4];
    #pragma unroll
    for (int i = 0; i < 4; ++i) af[i]  = *(const short8*)&At[wr*64 + i*16 + l15][l4*8];
    #pragma unroll
    for (int i = 0; i < 4; ++i) bfv[i] = *(const short8*)&Bt[wc*64 + i*16 + l15][l4*8];
    #pragma unroll
    for (int i = 0; i < 4; ++i)
      #pragma unroll
      for (int j = 0; j < 4; ++j)
        acc[i][j] = mfma16(af[i], bfv[j], acc[i][j]);
    __syncthreads();
  }
  #pragma unroll
  for (int i = 0; i < 4; ++i){
    const int r0 = rowBase + wr*64 + i*16 + l4*4;
    #pragma unroll
    for (int j = 0; j < 4; ++j){
      const int c = colBase + wc*64 + j*16 + l15;
      const float bb = bias[c];
      #pragma unroll
      for (int jr = 0; jr < 4; ++jr){
        const float v = acc[i][j][jr] + bb;
        const long rr = r0 + jr;
        if (!transposed){
          out[rr * 512 + c] = f2bf(v);
        } else {
          const long m = rr >> 7, s = rr & 127;
          out[(m * 512 + c) * 128 + s] = f2bf(v);
        }
      }
    }
  }
}

// ---------------- attention: per (m, 32-row q block) ----------------------
__global__ __launch_bounds__(256) void attn_kernel(const unsigned short* __restrict__ q,
                                                   const unsigned short* __restrict__ k,
                                                   const unsigned short* __restrict__ vT,
                                                   const int* __restrict__ mask,
                                                   unsigned short* __restrict__ attn){
  __shared__ __align__(16) char smem[58880];
  unsigned short (*q_lds)[520] = (unsigned short (*)[520])smem;          // [0,33280)
  unsigned short (*k_lds)[40]  = (unsigned short (*)[40])(smem + 33280); // [33280,43520)
  float (*lg)[132]             = (float (*)[132])(smem + 33280);         // overlaps k_lds (after K-loop)
  unsigned short (*w_lds)[136] = (unsigned short (*)[136])(smem + 50176);
  unsigned short (*v_lds)[136] = (unsigned short (*)[136])smem;          // overlaps q_lds (after softmax)
  const int m = blockIdx.x >> 3, nb = blockIdx.x & 7;
  const int t = threadIdx.x, lane = t & 63, wid = t >> 6;
  const int l15 = lane & 15, l4 = lane >> 4;
  {
    const int r = t >> 3, c0 = (t & 7) * 64;
    const unsigned short* src = q + (long)(nb*32 + r) * 512 + c0;
    #pragma unroll
    for (int i = 0; i < 64; i += 8)
      *(short8*)&q_lds[r][c0 + i] = *(const short8*)(src + i);
  }
  f32x4 zero = {0.f,0.f,0.f,0.f};
  f32x4 acc[2][2];
  acc[0][0]=zero; acc[0][1]=zero; acc[1][0]=zero; acc[1][1]=zero;
  const int kr = t >> 1, kh = (t & 1) * 16;
  const unsigned short* kbase = k + (long)m * 128 * 512;
  for (int ks = 0; ks < 16; ++ks){
    const int k0 = ks * 32;
    const unsigned short* src = kbase + (long)kr * 512 + k0 + kh;
    *(short8*)&k_lds[kr][kh]     = *(const short8*)src;
    *(short8*)&k_lds[kr][kh + 8] = *(const short8*)(src + 8);
    __syncthreads();
    short8 af[2], bfv[2];
    #pragma unroll
    for (int i = 0; i < 2; ++i) af[i]  = *(const short8*)&q_lds[i*16 + l15][k0 + l4*8];
    #pragma unroll
    for (int i = 0; i < 2; ++i) bfv[i] = *(const short8*)&k_lds[wid*32 + i*16 + l15][l4*8];
    #pragma unroll
    for (int i = 0; i < 2; ++i)
      #pragma unroll
      for (int j = 0; j < 2; ++j)
        acc[i][j] = mfma16(af[i], bfv[j], acc[i][j]);
    __syncthreads();
  }
  const float scale = 0.04419417382415922f; // 1/sqrt(512)
  #pragma unroll
  for (int i = 0; i < 2; ++i)
    #pragma unroll
    for (int j = 0; j < 2; ++j)
      #pragma unroll
      for (int jr = 0; jr < 4; ++jr)
        lg[i*16 + l4*4 + jr][wid*32 + j*16 + l15] = acc[i][j][jr] * scale;
  __syncthreads();
  {
    const int row = t >> 3, u = t & 7;
    const int* mrow = mask + m * 128;
    float vals[16];
    float mx = -3.0e38f;
    #pragma unroll
    for (int i = 0; i < 16; ++i){
      const int s = u*16 + i;
      const float vv = (mrow[s] == 0) ? -3.0e38f : lg[row][s];
      vals[i] = vv;
      mx = fmaxf(mx, vv);
    }
    mx = fmaxf(mx, __shfl_xor(mx, 1));
    mx = fmaxf(mx, __shfl_xor(mx, 2));
    mx = fmaxf(mx, __shfl_xor(mx, 4));
    float sum = 0.f;
    #pragma unroll
    for (int i = 0; i < 16; ++i){
      const float e = __expf(vals[i] - mx);
      vals[i] = e;
      sum += e;
    }
    sum += __shfl_xor(sum, 1);
    sum += __shfl_xor(sum, 2);
    sum += __shfl_xor(sum, 4);
    const float inv = (sum > 0.f) ? (1.f / sum) : 0.f;
    #pragma unroll
    for (int i = 0; i < 16; i += 4){
      u16x4 o = { f2bf(vals[i]*inv), f2bf(vals[i+1]*inv),
                  f2bf(vals[i+2]*inv), f2bf(vals[i+3]*inv) };
      *(u16x4*)&w_lds[row][u*16 + i] = o;
    }
  }
  const long rowb = (long)m * 256 + nb * 32;
  const unsigned short* vbase = vT + (long)m * 512 * 128;
  for (int db = 0; db < 4; ++db){
    __syncthreads();
    {
      const int r = t >> 1, h = (t & 1) * 64;
      const unsigned short* src = vbase + (long)(db*128 + r) * 128 + h;
      #pragma unroll
      for (int i = 0; i < 64; i += 8)
        *(short8*)&v_lds[r][h + i] = *(const short8*)(src + i);
    }
    __syncthreads();
    f32x4 pacc[2][2];
    pacc[0][0]=zero; pacc[0][1]=zero; pacc[1][0]=zero; pacc[1][1]=zero;
    #pragma unroll
    for (int ks2 = 0; ks2 < 4; ++ks2){
      short8 wf[2], vf[2];
      #pragma unroll
      for (int i = 0; i < 2; ++i) wf[i] = *(const short8*)&w_lds[i*16 + l15][ks2*32 + l4*8];
      #pragma unroll
      for (int i = 0; i < 2; ++i) vf[i] = *(const short8*)&v_lds[wid*32 + i*16 + l15][ks2*32 + l4*8];
      #pragma unroll
      for (int i = 0; i < 2; ++i)
        #pragma unroll
        for (int j = 0; j < 2; ++j)
          pacc[i][j] = mfma16(wf[i], vf[j], pacc[i][j]);
    }
    #pragma unroll
    for (int i = 0; i < 2; ++i)
      #pragma unroll
      for (int j = 0; j < 2; ++j)
        #pragma unroll
        for (int jr = 0; jr < 4; ++jr)
          attn[(rowb + i*16 + l4*4 + jr) * 512 + db*128 + wid*32 + j*16 + l15] =
              f2bf(pacc[i][j][jr]);
  }
}

// ---------------- fused: o=attn*Wo^T+bo -> LN2 -> lin=oln*Wl^T+bl -> LN3 ---
__global__ __launch_bounds__(512) void fused_out_kernel(
    const unsigned short* __restrict__ attn,
    const unsigned short* __restrict__ Wo, const float* __restrict__ bo,
    const unsigned short* __restrict__ Wl, const float* __restrict__ bl,
    const float* __restrict__ g2, const float* __restrict__ b2,
    const float* __restrict__ g3, const float* __restrict__ b3,
    float* __restrict__ out){
  extern __shared__ char smem[];
  unsigned short (*oln)[520] = (unsigned short (*)[520])smem;            // 66560 B
  unsigned short (*Bt)[40]   = (unsigned short (*)[40])(smem + 66560);   // 40960 B
  unsigned short (*At)[40]   = (unsigned short (*)[40])(smem + 107520);  // 5120 B
  float (*rs1)[4]            = (float (*)[4])(smem + 112640);            // 1024 B used
  float (*rs2)[4]            = (float (*)[4])(smem + 114688);
  const int t = threadIdx.x, lane = t & 63, wid = t >> 6;
  const int l15 = lane & 15, l4 = lane >> 4;
  const int wr = wid >> 2, wc = wid & 3;
  const long rows0 = (long)blockIdx.x * 64;
  f32x4 zero = {0.f,0.f,0.f,0.f};
  f32x4 acc[2][8];
  #pragma unroll
  for (int i = 0; i < 2; ++i)
    #pragma unroll
    for (int j = 0; j < 8; ++j) acc[i][j] = zero;
  const int ar = t >> 3, ac = (t & 7) * 4;
  const int br = t >> 2, bc = (t & 3) * 8;
  // phase 1: o = attn * Wo^T
  for (int ks = 0; ks < 16; ++ks){
    const int k0 = ks * 32;
    *(u16x4*)&At[ar][ac] = *(const u16x4*)(attn + (rows0 + ar) * 512 + k0 + ac);
    #pragma unroll
    for (int p = 0; p < 4; ++p){
      const int r = p * 128 + br;
      *(short8*)&Bt[r][bc] = *(const short8*)(Wo + (long)r * 512 + k0 + bc);
    }
    __syncthreads();
    short8 af0 = *(const short8*)&At[wr*32 + l15][l4*8];
    short8 af1 = *(const short8*)&At[wr*32 + 16 + l15][l4*8];
    #pragma unroll
    for (int ni = 0; ni < 8; ++ni){
      short8 bfr = *(const short8*)&Bt[wc*128 + ni*16 + l15][l4*8];
      acc[0][ni] = mfma16(af0, bfr, acc[0][ni]);
      acc[1][ni] = mfma16(af1, bfr, acc[1][ni]);
    }
    __syncthreads();
  }
  // bias + LN2
  float ps1[2][4], ps2[2][4];
  #pragma unroll
  for (int mi = 0; mi < 2; ++mi)
    #pragma unroll
    for (int jr = 0; jr < 4; ++jr){ ps1[mi][jr] = 0.f; ps2[mi][jr] = 0.f; }
  #pragma unroll
  for (int mi = 0; mi < 2; ++mi)
    #pragma unroll
    for (int ni = 0; ni < 8; ++ni){
      const int col = wc*128 + ni*16 + l15;
      const float bb = bo[col];
      #pragma unroll
      for (int jr = 0; jr < 4; ++jr){
        const float v = acc[mi][ni][jr] + bb;
        acc[mi][ni][jr] = v;
        ps1[mi][jr] += v;
        ps2[mi][jr] += v * v;
      }
    }
  #pragma unroll
  for (int mk = 1; mk < 16; mk <<= 1)
    #pragma unroll
    for (int mi = 0; mi < 2; ++mi)
      #pragma unroll
      for (int jr = 0; jr < 4; ++jr){
        ps1[mi][jr] += __shfl_xor(ps1[mi][jr], mk);
        ps2[mi][jr] += __shfl_xor(ps2[mi][jr], mk);
      }
  if (l15 == 0){
    #pragma unroll
    for (int mi = 0; mi < 2; ++mi)
      #pragma unroll
      for (int jr = 0; jr < 4; ++jr){
        const int r = wr*32 + mi*16 + l4*4 + jr;
        rs1[r][wc] = ps1[mi][jr];
        rs2[r][wc] = ps2[mi][jr];
      }
  }
  __syncthreads();
  float mu2[2][4], rstd2[2][4];
  #pragma unroll
  for (int mi = 0; mi < 2; ++mi)
    #pragma unroll
    for (int jr = 0; jr < 4; ++jr){
      const int r = wr*32 + mi*16 + l4*4 + jr;
      const float s  = rs1[r][0] + rs1[r][1] + rs1[r][2] + rs1[r][3];
      const float sq = rs2[r][0] + rs2[r][1] + rs2[r][2] + rs2[r][3];
      const float m_ = s * (1.f/512.f);
      mu2[mi][jr] = m_;
      rstd2[mi][jr] = rsqrtf(sq * (1.f/512.f) - m_*m_ + 1e-5f);
    }
  #pragma unroll
  for (int mi = 0; mi < 2; ++mi)
    #pragma unroll
    for (int ni = 0; ni < 8; ++ni){
      const int col = wc*128 + ni*16 + l15;
      const float gg = g2[col], bb = b2[col];
      #pragma unroll
      for (int jr = 0; jr < 4; ++jr){
        const int r = wr*32 + mi*16 + l4*4 + jr;
        const float ov = (acc[mi][ni][jr] - mu2[mi][jr]) * rstd2[mi][jr] * gg + bb;
        oln[r][col] = f2bf(ov);
      }
    }
  __syncthreads();
  // phase 2: lin = oln * Wl^T
  #pragma unroll
  for (int i = 0; i < 2; ++i)
    #pragma unroll
    for (int j = 0; j < 8; ++j) acc[i][j] = zero;
  for (int ks = 0; ks < 16; ++ks){
    const int k0 = ks * 32;
    #pragma unroll
    for (int p = 0; p < 4; ++p){
      const int r = p * 128 + br;
      *(short8*)&Bt[r][bc] = *(const short8*)(Wl + (long)r * 512 + k0 + bc);
    }
    __syncthreads();
    short8 af0 = *(const short8*)&oln[wr*32 + l15][k0 + l4*8];
    short8 af1 = *(const short8*)&oln[wr*32 + 16 + l15][k0 + l4*8];
    #pragma unroll
    for (int ni = 0; ni < 8; ++ni){
      short8 bfr = *(const short8*)&Bt[wc*128 + ni*16 + l15][l4*8];
      acc[0][ni] = mfma16(af0, bfr, acc[0][ni]);
      acc[1][ni] = mfma16(af1, bfr, acc[1][ni]);
    }
    __syncthreads();
  }
  // residual + LN3
  #pragma unroll
  for (int mi = 0; mi < 2; ++mi)
    #pragma unroll
    for (int jr = 0; jr < 4; ++jr){ ps1[mi][jr] = 0.f; ps2[mi][jr] = 0.f; }
  #pragma unroll
  for (int mi = 0; mi < 2; ++mi)
    #pragma unroll
    for (int ni = 0; ni < 8; ++ni){
      const int col = wc*128 + ni*16 + l15;
      const float bb = bl[col];
      #pragma unroll
      for (int jr = 0; jr < 4; ++jr){
        const int r = wr*32 + mi*16 + l4*4 + jr;
        const float y = acc[mi][ni][jr] + bb + bf2f(oln[r][col]);
        acc[mi][ni][jr] = y;
        ps1[mi][jr] += y;
        ps2[mi][jr] += y * y;
      }
    }
  #pragma unroll
  for (int mk = 1; mk < 16; mk <<= 1)
    #pragma unroll
    for (int mi = 0; mi < 2; ++mi)
      #pragma unroll
      for (int jr = 0; jr < 4; ++jr){
        ps1[mi][jr] += __shfl_xor(ps1[mi][jr], mk);
        ps2[mi][jr] += __shfl_xor(ps2[mi][jr], mk);
      }
  if (l15 == 0){
    #pragma unroll
    for (int mi = 0; mi < 2; ++mi)
      #pragma unroll
      for (int jr = 0; jr < 4; ++jr){
        const int r = wr*32 + mi*16 + l4*4 + jr;
        rs1[r][wc] = ps1[mi][jr];
        rs2[r][wc] = ps2[mi][jr];
      }
  }
  __syncthreads();
  #pragma unroll
  for (int mi = 0; mi < 2; ++mi)
    #pragma unroll
    for (int jr = 0; jr < 4; ++jr){
      const int r = wr*32 + mi*16 + l4*4 + jr;
      const float s  = rs1[r][0] + rs1[r][1] + rs1[r][2] + rs1[r][3];
      const float sq = rs2[r][0] + rs2[r][1] + rs2[r][2] + rs2[r][3];
      const float m_ = s * (1.f/512.f);
      mu2[mi][jr] = m_;
      rstd2[mi][jr] = rsqrtf(sq * (1.f/512.f) - m_*m_ + 1e-5f);
    }
  #pragma unroll
  for (int mi = 0; mi < 2; ++mi)
    #pragma unroll
    for (int ni = 0; ni < 8; ++ni){
      const int col = wc*128 + ni*16 + l15;
      const float gg = g3[col], bb = b3[col];
      #pragma unroll
      for (int jr = 0; jr < 4; ++jr){
        const int r = wr*32 + mi*16 + l4*4 + jr;
        out[(rows0 + r) * 512 + col] =
            (acc[mi][ni][jr] - mu2[mi][jr]) * rstd2[mi][jr] * gg + bb;
      }
    }
}

extern "C" void kernel_launch(void* const* d_in, const int* in_sizes, int n_in,
                              void* d_out, int out_size, void* d_ws, size_t ws_size,
                              hipStream_t stream){
  const float* video = (const float*)d_in[0];
  const float* music = (const float*)d_in[1];
  const int*   mask  = (const int*)d_in[2];
  const float* ln1g  = (const float*)d_in[3];
  const float* ln1b  = (const float*)d_in[4];
  const float* Wq = (const float*)d_in[5];  const float* bq = (const float*)d_in[6];
  const float* Wk = (const float*)d_in[7];  const float* bk = (const float*)d_in[8];
  const float* Wv = (const float*)d_in[9];  const float* bv = (const float*)d_in[10];
  const float* Wo = (const float*)d_in[11]; const float* bo = (const float*)d_in[12];
  const float* Wl = (const float*)d_in[13]; const float* bl = (const float*)d_in[14];
  const float* g2 = (const float*)d_in[15]; const float* b2 = (const float*)d_in[16];
  const float* g3 = (const float*)d_in[17]; const float* b3 = (const float*)d_in[18];

  // d_out doubles as scratch for stage-1/2 intermediates (dead before final write)
  char* ob = (char*)d_out;
  unsigned short* mln   = (unsigned short*)ob;                  // [65536][512] bf16
  unsigned short* kbuf  = (unsigned short*)(ob + 67108864);     // [65536][512] bf16
  unsigned short* vTbuf = (unsigned short*)(ob + 134217728);    // [512][512][128] bf16
  float* outp = (float*)d_out;

  char* wsb = (char*)d_ws;
  unsigned short* attnb = (unsigned short*)wsb;                 // [131072][512] bf16
  unsigned short* Wq_bf = (unsigned short*)(wsb + 134217728);
  unsigned short* Wk_bf = Wq_bf + 262144;
  unsigned short* Wv_bf = Wk_bf + 262144;
  unsigned short* Wo_bf = Wv_bf + 262144;
  unsigned short* Wl_bf = Wo_bf + 262144;
  unsigned short* q_ws  = Wl_bf + 262144;                       // [256][512] bf16
  unsigned short* vln   = q_ws + 131072;                        // [256][512] bf16

  cvt_f32_bf16<<<256, 256, 0, stream>>>(Wq, Wq_bf);
  cvt_f32_bf16<<<256, 256, 0, stream>>>(Wk, Wk_bf);
  cvt_f32_bf16<<<256, 256, 0, stream>>>(Wv, Wv_bf);
  cvt_f32_bf16<<<256, 256, 0, stream>>>(Wo, Wo_bf);
  cvt_f32_bf16<<<256, 256, 0, stream>>>(Wl, Wl_bf);

  ln_rows<<<16384, 256, 0, stream>>>(music, ln1g, ln1b, mln, 65536);
  ln_rows<<<64,    256, 0, stream>>>(video, ln1g, ln1b, vln, 256);

  gemm_bt<<<dim3(4, 2),   256, 0, stream>>>(vln, Wq_bf, bq, q_ws, 0);
  gemm_bt<<<dim3(4, 512), 256, 0, stream>>>(mln, Wk_bf, bk, kbuf, 0);
  gemm_bt<<<dim3(4, 512), 256, 0, stream>>>(mln, Wv_bf, bv, vTbuf, 1);

  attn_kernel<<<4096, 256, 0, stream>>>(q_ws, kbuf, vTbuf, mask, attnb);

  (void)hipFuncSetAttribute(reinterpret_cast<const void*>(fused_out_kernel),
                            hipFuncAttributeMaxDynamicSharedMemorySize, 116736);
  fused_out_kernel<<<2048, 512, 116736, stream>>>(attnb, Wo_bf, bo, Wl_bf, bl,
                                                  g2, b2, g3, b3, outp);
}